// Round 1
// 546.730 us; speedup vs baseline: 1.2200x; 1.2200x over previous
//
#include <hip/hip_runtime.h>
#include <math.h>

// Problem constants
#define NPTS  32768      // 8 * 4096 points
#define NPAIR 4096       // 64 * 64 (oc,ic) pairs
#define NC    23         // basis combos
#define TPB   256
#define PPT   4                      // points per thread -> dwordx4 stores
#define PTS_PER_BLOCK (TPB * PPT)    // 1024 points per block
#define PT    64                     // pair tile per block (j-loop length)
#define NCP   24                     // padded coef row stride (16B-aligned rows)

// ---------------- compile-time constant tables ----------------
namespace cgen {
constexpr double PI = 3.14159265358979323846264338327950288;
constexpr double fact(int n) { double r = 1; for (int i = 2; i <= n; ++i) r *= i; return r; }
constexpr double comb(int n, int k) { double r = 1; for (int i = 0; i < k; ++i) r = r * (n - i) / (i + 1); return r; }
constexpr double csqrt(double x) { double g = x > 1 ? x : 1.0; for (int i = 0; i < 100; ++i) g = 0.5 * (g + x / g); return g; }

struct Tables {
  int n[NC]; int l[NC]; int m[NC];
  double pref[NC];      // norm_r * Klm * (sqrt(2) if m != 0)
  double lag[NC][4];    // Laguerre poly coeffs (x^0..x^3)
};
constexpr Tables gen() {
  Tables t{};
  int idx = 0;
  for (int n = 1; n <= 4; ++n)
    for (int k = 0; k < 3; ++k)
      for (int m = -3; m <= 3; ++m) {
        int am = m < 0 ? -m : m;
        if (!(am <= k && k < n)) continue;
        t.n[idx] = n; t.l[idx] = k; t.m[idx] = m;
        double norm_r = csqrt((2.0 / n) * (2.0 / n) * (2.0 / n) * fact(n - k - 1) / (2.0 * n * fact(n + k)));
        double Klm = csqrt((2.0 * k + 1.0) / (4.0 * PI) * fact(k - am) / fact(k + am));
        t.pref[idx] = norm_r * Klm * (m != 0 ? csqrt(2.0) : 1.0);
        int kk = n - k - 1, a = 2 * k + 1;
        for (int i = 0; i < 4; ++i) t.lag[idx][i] = 0.0;
        for (int i = 0; i <= kk; ++i)
          t.lag[idx][i] = ((i & 1) ? -1.0 : 1.0) * comb(kk + a, kk - i) / fact(i);
        ++idx;
      }
  return t;
}
constexpr Tables T = gen();
} // namespace cgen

// ---------------- kernel ----------------
__global__ __launch_bounds__(TPB)
void dcconv_poly_einsum(const float* __restrict__ pos,
                        const float* __restrict__ coef,
                        float* __restrict__ out) {
  __shared__ __align__(16) float lc[PT * NCP];   // 64 pairs x 24 floats = 6 KiB

  const int tid   = threadIdx.x;
  const int pt0   = blockIdx.x * PTS_PER_BLOCK + tid * PPT;  // first of 4 consecutive points
  const int pair0 = blockIdx.y * PT;

  // ---- stage coef slab into LDS (coalesced dword loads, padded rows) ----
  {
    const float* __restrict__ cb = coef + (size_t)pair0 * NC;   // contiguous 64*23 floats
#pragma unroll
    for (int i = tid; i < PT * NC; i += TPB) {
      const int row = i / NC;
      const int col = i - row * NC;
      lc[row * NCP + col] = cb[i];
    }
    if (tid < PT) lc[tid * NCP + NC] = 0.0f;   // zero pad column
  }

  // ---- per-point geometry + 23 basis values, 4 points per thread ----
  const float4* __restrict__ pv = reinterpret_cast<const float4*>(pos + (size_t)pt0 * 3);
  const float4 q0 = pv[0], q1 = pv[1], q2 = pv[2];
  // layout: q0={x0,y0,z0,x1} q1={y1,z1,x2,y2} q2={z2,x3,y3,z3}

  float p0[NC], p1[NC], p2[NC], p3[NC];

  auto evalpt = [&](float x, float y, float z, float (&pc)[NC]) {
    const float r   = sqrtf(x * x + y * y + z * z) + 1e-12f;
    const float ct  = z / r;
    const float st2 = fmaxf(1.0f - ct * ct, 0.0f);
    const float st  = sqrtf(st2);
    const float phi = atan2f(y, x);
    float sp, cp;
    sincosf(phi, &sp, &cp);
    const float c2p = cp * cp - sp * sp;
    const float s2p = 2.0f * sp * cp;

    float rho[5]; rho[0] = 0.0f; rho[1] = 2.0f * r; rho[2] = r; rho[3] = (2.0f / 3.0f) * r; rho[4] = 0.5f * r;
    float en[5];  en[0] = 0.0f;
    en[1] = expf(-r); en[2] = expf(-0.5f * r); en[3] = expf(-(1.0f / 3.0f) * r); en[4] = expf(-0.25f * r);

    float P[3][3] = {};
    P[0][0] = 1.0f;
    P[1][0] = ct;                    P[1][1] = -st;
    P[2][0] = 1.5f * ct * ct - 0.5f; P[2][1] = -3.0f * ct * st; P[2][2] = 3.0f * st2;

    float trig[5]; trig[0] = s2p; trig[1] = sp; trig[2] = 1.0f; trig[3] = cp; trig[4] = c2p;

#pragma unroll
    for (int c = 0; c < NC; ++c) {
      const int n = cgen::T.n[c], l = cgen::T.l[c], m = cgen::T.m[c];
      const int am = m < 0 ? -m : m;
      const float rh = rho[n];
      const float L = (float)cgen::T.lag[c][0]
                    + rh * ((float)cgen::T.lag[c][1]
                    + rh * ((float)cgen::T.lag[c][2]
                    + rh *  (float)cgen::T.lag[c][3]));
      const float rl = (l == 0) ? 1.0f : ((l == 1) ? rh : rh * rh);
      pc[c] = (float)cgen::T.pref[c] * en[n] * rl * L * P[l][am] * trig[m + 2];
    }
  };

  evalpt(q0.x, q0.y, q0.z, p0);
  evalpt(q0.w, q1.x, q1.y, p1);
  evalpt(q1.z, q1.w, q2.x, p2);
  evalpt(q2.y, q2.z, q2.w, p3);

  __syncthreads();

  // ---- einsum slice: PT pairs, 92 FMAs + 6 uniform ds_read_b128 + 1 dwordx4 store each ----
  const float4* __restrict__ lrow = reinterpret_cast<const float4*>(lc);  // 6 float4 per row
  float* __restrict__ optr = out + (size_t)pair0 * NPTS + pt0;

#define G4(CV, B)                                                                      \
  a0 = fmaf(CV.x, p0[(B)+0], a0); a1 = fmaf(CV.x, p1[(B)+0], a1);                       \
  a2 = fmaf(CV.x, p2[(B)+0], a2); a3 = fmaf(CV.x, p3[(B)+0], a3);                       \
  a0 = fmaf(CV.y, p0[(B)+1], a0); a1 = fmaf(CV.y, p1[(B)+1], a1);                       \
  a2 = fmaf(CV.y, p2[(B)+1], a2); a3 = fmaf(CV.y, p3[(B)+1], a3);                       \
  a0 = fmaf(CV.z, p0[(B)+2], a0); a1 = fmaf(CV.z, p1[(B)+2], a1);                       \
  a2 = fmaf(CV.z, p2[(B)+2], a2); a3 = fmaf(CV.z, p3[(B)+2], a3);                       \
  a0 = fmaf(CV.w, p0[(B)+3], a0); a1 = fmaf(CV.w, p1[(B)+3], a1);                       \
  a2 = fmaf(CV.w, p2[(B)+3], a2); a3 = fmaf(CV.w, p3[(B)+3], a3);

#define G3(CV, B)                                                                      \
  a0 = fmaf(CV.x, p0[(B)+0], a0); a1 = fmaf(CV.x, p1[(B)+0], a1);                       \
  a2 = fmaf(CV.x, p2[(B)+0], a2); a3 = fmaf(CV.x, p3[(B)+0], a3);                       \
  a0 = fmaf(CV.y, p0[(B)+1], a0); a1 = fmaf(CV.y, p1[(B)+1], a1);                       \
  a2 = fmaf(CV.y, p2[(B)+1], a2); a3 = fmaf(CV.y, p3[(B)+1], a3);                       \
  a0 = fmaf(CV.z, p0[(B)+2], a0); a1 = fmaf(CV.z, p1[(B)+2], a1);                       \
  a2 = fmaf(CV.z, p2[(B)+2], a2); a3 = fmaf(CV.z, p3[(B)+2], a3);

#pragma unroll 2
  for (int j = 0; j < PT; ++j) {
    const float4 c0 = lrow[0], c1 = lrow[1], c2 = lrow[2],
                 c3 = lrow[3], c4 = lrow[4], c5 = lrow[5];
    lrow += 6;

    float a0 = 0.0f, a1 = 0.0f, a2 = 0.0f, a3 = 0.0f;
    G4(c0, 0) G4(c1, 4) G4(c2, 8) G4(c3, 12) G4(c4, 16) G3(c5, 20)

    *reinterpret_cast<float4*>(optr) = make_float4(a0, a1, a2, a3);
    optr += NPTS;
  }
#undef G4
#undef G3
}

// ---------------- launch ----------------
extern "C" void kernel_launch(void* const* d_in, const int* in_sizes, int n_in,
                              void* d_out, int out_size, void* d_ws, size_t ws_size,
                              hipStream_t stream) {
  const float* pos  = (const float*)d_in[0];   // (8, 4096, 3) fp32
  const float* coef = (const float*)d_in[1];   // (64, 64, 23) fp32
  float* out = (float*)d_out;                  // (64, 64, 8, 4096) fp32

  dim3 grid(NPTS / PTS_PER_BLOCK, NPAIR / PT); // (32, 64) = 2048 blocks
  dim3 block(TPB);
  hipLaunchKernelGGL(dcconv_poly_einsum, grid, block, 0, stream, pos, coef, out);
}

// Round 2
// 540.078 us; speedup vs baseline: 1.2351x; 1.0123x over previous
//
#include <hip/hip_runtime.h>
#include <math.h>

// Problem constants
#define NPTS  32768      // 8 * 4096 points
#define NPAIR 4096       // 64 * 64 (oc,ic) pairs
#define NC    23         // basis combos
#define TPB   256
#define PPT   2                      // points per thread -> dwordx2 stores, low VGPR
#define PTS_PER_BLOCK (TPB * PPT)    // 512 points per block
#define PT    64                     // pair tile per block (j-loop length)
#define NCP   24                     // padded coef row stride (16B-aligned rows)

// ---------------- compile-time constant tables ----------------
namespace cgen {
constexpr double PI = 3.14159265358979323846264338327950288;
constexpr double fact(int n) { double r = 1; for (int i = 2; i <= n; ++i) r *= i; return r; }
constexpr double comb(int n, int k) { double r = 1; for (int i = 0; i < k; ++i) r = r * (n - i) / (i + 1); return r; }
constexpr double csqrt(double x) { double g = x > 1 ? x : 1.0; for (int i = 0; i < 100; ++i) g = 0.5 * (g + x / g); return g; }

struct Tables {
  int n[NC]; int l[NC]; int m[NC];
  double pref[NC];      // norm_r * Klm * (sqrt(2) if m != 0)
  double lag[NC][4];    // Laguerre poly coeffs (x^0..x^3)
};
constexpr Tables gen() {
  Tables t{};
  int idx = 0;
  for (int n = 1; n <= 4; ++n)
    for (int k = 0; k < 3; ++k)
      for (int m = -3; m <= 3; ++m) {
        int am = m < 0 ? -m : m;
        if (!(am <= k && k < n)) continue;
        t.n[idx] = n; t.l[idx] = k; t.m[idx] = m;
        double norm_r = csqrt((2.0 / n) * (2.0 / n) * (2.0 / n) * fact(n - k - 1) / (2.0 * n * fact(n + k)));
        double Klm = csqrt((2.0 * k + 1.0) / (4.0 * PI) * fact(k - am) / fact(k + am));
        t.pref[idx] = norm_r * Klm * (m != 0 ? csqrt(2.0) : 1.0);
        int kk = n - k - 1, a = 2 * k + 1;
        for (int i = 0; i < 4; ++i) t.lag[idx][i] = 0.0;
        for (int i = 0; i <= kk; ++i)
          t.lag[idx][i] = ((i & 1) ? -1.0 : 1.0) * comb(kk + a, kk - i) / fact(i);
        ++idx;
      }
  return t;
}
constexpr Tables T = gen();
} // namespace cgen

// ---------------- kernel ----------------
__global__ __launch_bounds__(TPB, 4)
void dcconv_poly_einsum(const float* __restrict__ pos,
                        const float* __restrict__ coef,
                        float* __restrict__ out) {
  // +1 guard row so the last prefetch never reads out of bounds
  __shared__ __align__(16) float lc[(PT + 1) * NCP];   // 65 rows x 24 floats = 6.1 KiB

  const int tid   = threadIdx.x;
  const int pt0   = blockIdx.x * PTS_PER_BLOCK + tid * PPT;  // first of 2 consecutive points
  const int pair0 = blockIdx.y * PT;

  // ---- stage coef slab into LDS (coalesced dword loads, padded rows) ----
  {
    const float* __restrict__ cb = coef + (size_t)pair0 * NC;   // contiguous 64*23 floats
#pragma unroll
    for (int i = tid; i < PT * NC; i += TPB) {
      const int row = i / NC;
      const int col = i - row * NC;
      lc[row * NCP + col] = cb[i];
    }
  }

  // ---- per-point geometry + 23 basis values, 2 points per thread ----
  const float2* __restrict__ pv = reinterpret_cast<const float2*>(pos + (size_t)pt0 * 3);
  const float2 f0 = pv[0], f1 = pv[1], f2 = pv[2];
  // layout: f0={x0,y0} f1={z0,x1} f2={y1,z1}

  float p0[NC], p1[NC];

  auto evalpt = [&](float x, float y, float z, float (&pc)[NC]) {
    const float rxy2 = x * x + y * y;
    const float r    = sqrtf(rxy2 + z * z) + 1e-12f;
    const float ct   = z / r;
    const float st   = sqrtf(rxy2) / r;        // == sqrt(clip(1-ct^2)) exactly, >= 0
    const float st2  = st * st;
    // cos(phi), sin(phi) without atan2/sincos; guarded rsqrt (st=0 makes m!=0 terms vanish)
    const float invq = rsqrtf(fmaxf(rxy2, 1e-30f));
    const float cp   = x * invq;
    const float sp   = y * invq;
    const float c2p  = (cp - sp) * (cp + sp);  // cos(2 phi)
    const float s2p  = 2.0f * sp * cp;         // sin(2 phi)

    float rho[5]; rho[0] = 0.0f; rho[1] = 2.0f * r; rho[2] = r; rho[3] = (2.0f / 3.0f) * r; rho[4] = 0.5f * r;
    float en[5];  en[0] = 0.0f;
    en[4] = expf(-0.25f * r);
    en[2] = en[4] * en[4];
    en[1] = en[2] * en[2];
    en[3] = expf(-(1.0f / 3.0f) * r);

    float P[3][3] = {};
    P[0][0] = 1.0f;
    P[1][0] = ct;                    P[1][1] = -st;
    P[2][0] = 1.5f * ct * ct - 0.5f; P[2][1] = -3.0f * ct * st; P[2][2] = 3.0f * st2;

    float trig[5]; trig[0] = s2p; trig[1] = sp; trig[2] = 1.0f; trig[3] = cp; trig[4] = c2p;

#pragma unroll
    for (int c = 0; c < NC; ++c) {
      const int n = cgen::T.n[c], l = cgen::T.l[c], m = cgen::T.m[c];
      const int am = m < 0 ? -m : m;
      const float rh = rho[n];
      const float L = (float)cgen::T.lag[c][0]
                    + rh * ((float)cgen::T.lag[c][1]
                    + rh * ((float)cgen::T.lag[c][2]
                    + rh *  (float)cgen::T.lag[c][3]));
      const float rl = (l == 0) ? 1.0f : ((l == 1) ? rh : rh * rh);
      pc[c] = (float)cgen::T.pref[c] * en[n] * rl * L * P[l][am] * trig[m + 2];
    }
  };

  evalpt(f0.x, f0.y, f1.x, p0);
  evalpt(f1.y, f2.x, f2.y, p1);

  __syncthreads();

  // ---- einsum slice: PT pairs, 46 FMAs + prefetched uniform ds_read_b128 + dwordx2 store ----
  const float4* __restrict__ lrow = reinterpret_cast<const float4*>(lc);  // 6 float4 per row
  float* __restrict__ optr = out + (size_t)pair0 * NPTS + pt0;

#define G4(CV, B)                                                  \
  a0 = fmaf(CV.x, p0[(B)+0], a0); a1 = fmaf(CV.x, p1[(B)+0], a1);  \
  a0 = fmaf(CV.y, p0[(B)+1], a0); a1 = fmaf(CV.y, p1[(B)+1], a1);  \
  a0 = fmaf(CV.z, p0[(B)+2], a0); a1 = fmaf(CV.z, p1[(B)+2], a1);  \
  a0 = fmaf(CV.w, p0[(B)+3], a0); a1 = fmaf(CV.w, p1[(B)+3], a1);

#define G3(CV, B)                                                  \
  a0 = fmaf(CV.x, p0[(B)+0], a0); a1 = fmaf(CV.x, p1[(B)+0], a1);  \
  a0 = fmaf(CV.y, p0[(B)+1], a0); a1 = fmaf(CV.y, p1[(B)+1], a1);  \
  a0 = fmaf(CV.z, p0[(B)+2], a0); a1 = fmaf(CV.z, p1[(B)+2], a1);

  float4 c0 = lrow[0], c1 = lrow[1], c2 = lrow[2],
         c3 = lrow[3], c4 = lrow[4], c5 = lrow[5];

#pragma unroll 4
  for (int j = 0; j < PT; ++j) {
    // prefetch next row's coefficients (guard row makes j==PT-1 safe)
    const float4* nrow = lrow + 6 * (j + 1);
    const float4 n0 = nrow[0], n1 = nrow[1], n2 = nrow[2],
                 n3 = nrow[3], n4 = nrow[4], n5 = nrow[5];

    float a0 = 0.0f, a1 = 0.0f;
    G4(c0, 0) G4(c1, 4) G4(c2, 8) G4(c3, 12) G4(c4, 16) G3(c5, 20)

    float2 res; res.x = a0; res.y = a1;
    *reinterpret_cast<float2*>(optr) = res;
    optr += NPTS;

    c0 = n0; c1 = n1; c2 = n2; c3 = n3; c4 = n4; c5 = n5;
  }
#undef G4
#undef G3
}

// ---------------- launch ----------------
extern "C" void kernel_launch(void* const* d_in, const int* in_sizes, int n_in,
                              void* d_out, int out_size, void* d_ws, size_t ws_size,
                              hipStream_t stream) {
  const float* pos  = (const float*)d_in[0];   // (8, 4096, 3) fp32
  const float* coef = (const float*)d_in[1];   // (64, 64, 23) fp32
  float* out = (float*)d_out;                  // (64, 64, 8, 4096) fp32

  dim3 grid(NPTS / PTS_PER_BLOCK, NPAIR / PT); // (64, 64) = 4096 blocks
  dim3 block(TPB);
  hipLaunchKernelGGL(dcconv_poly_einsum, grid, block, 0, stream, pos, coef, out);
}